// Round 1
// baseline (8297.401 us; speedup 1.0000x reference)
//
#include <hip/hip_runtime.h>
#include <cstdint>

// ---------------- problem constants ----------------
#define TT 512
#define BB 64
#define DD 1024
#define HH 1024
#define NWG 128          // persistent workgroups; each owns 8 hidden units
#define KTOT 64          // k-tiles of 32 over K=2048 ([X | H])

typedef __attribute__((ext_vector_type(8))) __bf16 bf16x8;
typedef __attribute__((ext_vector_type(4))) float f32x4;

// ---- workspace layout (bytes) ----
// Xq   bf16[TT*BB*DD]            @ 0            (67,108,864)
// WhB  bf16[NWG*KTOT*2*64*8]     @ 67,108,864   (16,777,216)
// Hq   bf16[(TT+1)*BB*HH]        @ 83,886,080   (67,239,936)
// flags int[(TT+1)*NWG]          @ 151,126,016  (   262,656)
#define WS_XQ    0
#define WS_WHB   67108864ULL
#define WS_HQ    83886080ULL
#define WS_FLAGS 151126016ULL
#define FLAGS_BYTES ((TT + 1) * NWG * 4)

__device__ __forceinline__ unsigned short f2bf(float f) {
    unsigned int u = __float_as_uint(f);
    u = (u + 0x7fffu + ((u >> 16) & 1u)) >> 16;
    return (unsigned short)u;
}

__device__ __forceinline__ float sigm(float x) {
    return 1.0f / (1.0f + __expf(-x));
}
__device__ __forceinline__ float tanh_f(float x) {
    float a = fabsf(x);
    float e = __expf(-2.0f * a);
    float t = (1.0f - e) / (1.0f + e);
    return copysignf(t, x);
}

__device__ __forceinline__ unsigned long long pack4bf(float a, float b, float c, float d) {
    return (unsigned long long)f2bf(a)
         | ((unsigned long long)f2bf(b) << 16)
         | ((unsigned long long)f2bf(c) << 32)
         | ((unsigned long long)f2bf(d) << 48);
}

// ---------------- kernel 1: convert X fp32 -> bf16 ----------------
__global__ void cvt_x(const float* __restrict__ X, unsigned short* __restrict__ Xq) {
    int i = blockIdx.x * blockDim.x + threadIdx.x;   // one thread per 8 elems
    const int n8 = TT * BB * DD / 8;
    if (i >= n8) return;
    const float4* s = (const float4*)X;
    float4 a = s[2 * i], b = s[2 * i + 1];
    union { unsigned short u[8]; uint4 q; } r;
    r.u[0] = f2bf(a.x); r.u[1] = f2bf(a.y); r.u[2] = f2bf(a.z); r.u[3] = f2bf(a.w);
    r.u[4] = f2bf(b.x); r.u[5] = f2bf(b.y); r.u[6] = f2bf(b.z); r.u[7] = f2bf(b.w);
    ((uint4*)Xq)[i] = r.q;
}

// ---------------- kernel 2: pack [Wx;Wh] into B-fragment order ----------------
// Element order: (((wg*64 + kt)*2 + nt)*64 + lane) * 8 + m  == B-frag layout:
// lane holds B[k = kt*32 + (lane>>4)*8 + m][col = nt*16 + (lane&15)]
// col j (0..31): gate = j>>3 (i,f,o,c), h = wg*8 + (j&7). kt<32 -> Wx row k, else Wh row k-1024.
__global__ void pack_w(const float* __restrict__ Wxi, const float* __restrict__ Wxf,
                       const float* __restrict__ Wxo, const float* __restrict__ Wxc,
                       const float* __restrict__ Whi, const float* __restrict__ Whf,
                       const float* __restrict__ Who, const float* __restrict__ Whc,
                       unsigned short* __restrict__ WhB) {
    int tid = blockIdx.x * blockDim.x + threadIdx.x;      // 0 .. 1,048,575
    int lane = tid & 63;
    int nt   = (tid >> 6) & 1;
    int kt   = (tid >> 7) & 63;
    int wg   = tid >> 13;
    int j    = nt * 16 + (lane & 15);
    int gate = j >> 3;
    int h    = wg * 8 + (j & 7);
    int kb   = kt * 32 + ((lane >> 4) & 3) * 8;

    const float* Wx[4] = {Wxi, Wxf, Wxo, Wxc};
    const float* Wh[4] = {Whi, Whf, Who, Whc};
    const float* W = (kt < 32) ? (Wx[gate] + (size_t)kb * HH + h)
                               : (Wh[gate] + (size_t)(kb - 1024) * HH + h);
    union { unsigned short u[8]; uint4 q; } r;
#pragma unroll
    for (int m = 0; m < 8; ++m) r.u[m] = f2bf(W[(size_t)m * HH]);
    *(uint4*)(WhB + (size_t)tid * 8) = r.q;
}

// ---------------- kernel 3: persistent LSTM recurrence ----------------
// 128 WGs x 256 threads. LDS: 128KB weight slice + gate tile + h tile.
// Dynamic LDS = 131072 + 8704 + 2048 = 141824 bytes  (1 WG/CU -> all resident)
#define LDS_BYTES 141824

__global__ void __launch_bounds__(256)
lstm_seq(const unsigned short* __restrict__ Xq, const unsigned short* __restrict__ WhB,
         unsigned short* __restrict__ Hq, int* flags,
         const float* __restrict__ H0, const float* __restrict__ C0,
         const float* __restrict__ bi, const float* __restrict__ bfp,
         const float* __restrict__ bo, const float* __restrict__ bc,
         float* __restrict__ out) {
    extern __shared__ char smem[];
    unsigned short* ldsB = (unsigned short*)smem;              // 131072 B
    float* gtile = (float*)(smem + 131072);                    // [4 waves][16][34] fp32
    float* htile = (float*)(smem + 131072 + 8704);             // [4 waves][16][8]  fp32

    const int wg   = blockIdx.x;
    const int tid  = threadIdx.x;
    const int wv   = tid >> 6;
    const int lane = tid & 63;
    const int quad = lane >> 4;
    const int l15  = lane & 15;
    const int brow = wv * 16 + l15;          // batch row this lane serves (GEMM A / activation)

    // ---- stage per-WG weight slice into LDS (128 KB) ----
    {
        const uint4* src = (const uint4*)(WhB + (size_t)wg * 65536ULL);
        uint4* dst = (uint4*)ldsB;
        for (int i = tid; i < 8192; i += 256) dst[i] = src[i];
    }

    // ---- biases + C state in registers (h = wg*8 + quad + p*4) ----
    const int hq0 = wg * 8 + quad;
    float Bi0 = bi[hq0],  Bi1 = bi[hq0 + 4];
    float Bf0 = bfp[hq0], Bf1 = bfp[hq0 + 4];
    float Bo0 = bo[hq0],  Bo1 = bo[hq0 + 4];
    float Bc0 = bc[hq0],  Bc1 = bc[hq0 + 4];
    float Cr0 = C0[(size_t)brow * HH + hq0];
    float Cr1 = C0[(size_t)brow * HH + hq0 + 4];

    // ---- publish Hq[0] slice (agent scope -> LLC), then flag ----
    if (tid < 64) {
        const float* s = H0 + (size_t)tid * HH + wg * 8;
        unsigned long long a = pack4bf(s[0], s[1], s[2], s[3]);
        unsigned long long b = pack4bf(s[4], s[5], s[6], s[7]);
        unsigned long long* d = (unsigned long long*)(Hq + (size_t)tid * HH + wg * 8);
        __hip_atomic_store(d,     a, __ATOMIC_RELAXED, __HIP_MEMORY_SCOPE_AGENT);
        __hip_atomic_store(d + 1, b, __ATOMIC_RELAXED, __HIP_MEMORY_SCOPE_AGENT);
    }
    __syncthreads();   // barrier drains vmcnt before release
    if (tid == 0)
        __hip_atomic_store(&flags[wg], 1, __ATOMIC_RELEASE, __HIP_MEMORY_SCOPE_AGENT);

    for (int t = 0; t < TT; ++t) {
        f32x4 acc0 = {0.f, 0.f, 0.f, 0.f};
        f32x4 acc1 = {0.f, 0.f, 0.f, 0.f};

        // ---- X-part of GEMM (independent of other WGs; runs before the poll) ----
        const unsigned short* xrow = Xq + ((size_t)(t * BB + brow)) * DD + quad * 8;
#pragma unroll 8
        for (int kt = 0; kt < 32; ++kt) {
            bf16x8 a  = *(const bf16x8*)(xrow + kt * 32);
            bf16x8 b0 = *(const bf16x8*)(ldsB + ((kt * 2 + 0) * 64 + lane) * 8);
            bf16x8 b1 = *(const bf16x8*)(ldsB + ((kt * 2 + 1) * 64 + lane) * 8);
            acc0 = __builtin_amdgcn_mfma_f32_16x16x32_bf16(a, b0, acc0, 0, 0, 0);
            acc1 = __builtin_amdgcn_mfma_f32_16x16x32_bf16(a, b1, acc1, 0, 0, 0);
        }

        // ---- wait for all 128 H slices of step t ----
        if (tid < NWG) {
            const int* fp = flags + (size_t)t * NWG + tid;
            while (__hip_atomic_load(fp, __ATOMIC_RELAXED, __HIP_MEMORY_SCOPE_AGENT) == 0)
                __builtin_amdgcn_s_sleep(1);
        }
        __syncthreads();

        // ---- H-part of GEMM ----
        const unsigned short* hrow = Hq + ((size_t)(t * BB + brow)) * HH + quad * 8;
#pragma unroll 8
        for (int kt = 0; kt < 32; ++kt) {
            bf16x8 a  = *(const bf16x8*)(hrow + kt * 32);
            bf16x8 b0 = *(const bf16x8*)(ldsB + (((32 + kt) * 2 + 0) * 64 + lane) * 8);
            bf16x8 b1 = *(const bf16x8*)(ldsB + (((32 + kt) * 2 + 1) * 64 + lane) * 8);
            acc0 = __builtin_amdgcn_mfma_f32_16x16x32_bf16(a, b0, acc0, 0, 0, 0);
            acc1 = __builtin_amdgcn_mfma_f32_16x16x32_bf16(a, b1, acc1, 0, 0, 0);
        }

        // ---- C-frag (col=lane&15, row=quad*4+r) -> LDS gate tile (stride 34: conflict-free) ----
        float* gt = gtile + wv * 16 * 34;
#pragma unroll
        for (int r = 0; r < 4; ++r) {
            gt[(quad * 4 + r) * 34 + l15]      = acc0[r];
            gt[(quad * 4 + r) * 34 + 16 + l15] = acc1[r];
        }
        __syncthreads();

        // ---- activation: lane -> (row=l15, h pair = quad, quad+4) ----
        {
            const float* gtr = gt + l15 * 34;
            float i0 = sigm(gtr[0  + quad] + Bi0);
            float f0 = sigm(gtr[8  + quad] + Bf0);
            float o0 = sigm(gtr[16 + quad] + Bo0);
            float g0 = tanh_f(gtr[24 + quad] + Bc0);
            float Cn0 = f0 * Cr0 + i0 * g0;  Cr0 = Cn0;
            float h0v = o0 * tanh_f(Cn0);

            float i1 = sigm(gtr[0  + quad + 4] + Bi1);
            float f1 = sigm(gtr[8  + quad + 4] + Bf1);
            float o1 = sigm(gtr[16 + quad + 4] + Bo1);
            float g1 = tanh_f(gtr[24 + quad + 4] + Bc1);
            float Cn1 = f1 * Cr1 + i1 * g1;  Cr1 = Cn1;
            float h1v = o1 * tanh_f(Cn1);

            float* ht = htile + wv * 128;
            ht[l15 * 8 + quad]     = h0v;
            ht[l15 * 8 + quad + 4] = h1v;
        }
        __syncthreads();

        // ---- coalesced stores: fp32 row to out, bf16 row to Hq[t+1] (agent scope) ----
        if (lane < 32) {
            int r2 = lane >> 1, half = lane & 1;
            int b2 = wv * 16 + r2;
            float4 v = *(const float4*)(htile + wv * 128 + r2 * 8 + half * 4);
            *(float4*)(out + ((size_t)t * BB + b2) * HH + wg * 8 + half * 4) = v;
            unsigned long long pk = pack4bf(v.x, v.y, v.z, v.w);
            __hip_atomic_store(
                (unsigned long long*)(Hq + ((size_t)(t + 1) * BB + b2) * HH + wg * 8 + half * 4),
                pk, __ATOMIC_RELAXED, __HIP_MEMORY_SCOPE_AGENT);
            if (t == TT - 1) {   // H_f copy
                *(float4*)(out + (size_t)TT * BB * HH + (size_t)b2 * HH + wg * 8 + half * 4) = v;
            }
        }
        __syncthreads();   // drains all waves' vmcnt before release
        if (tid == 0)
            __hip_atomic_store(flags + (size_t)(t + 1) * NWG + wg, 1,
                               __ATOMIC_RELEASE, __HIP_MEMORY_SCOPE_AGENT);
    }

    // ---- C_f ----
    float* cf = out + (size_t)TT * BB * HH + (size_t)BB * HH;
    cf[(size_t)brow * HH + hq0]     = Cr0;
    cf[(size_t)brow * HH + hq0 + 4] = Cr1;
}

// ---------------- launch ----------------
extern "C" void kernel_launch(void* const* d_in, const int* in_sizes, int n_in,
                              void* d_out, int out_size, void* d_ws, size_t ws_size,
                              hipStream_t stream) {
    const float* X   = (const float*)d_in[0];
    const float* H0  = (const float*)d_in[1];
    const float* C0  = (const float*)d_in[2];
    const float* Wxi = (const float*)d_in[3];
    const float* Wxf = (const float*)d_in[4];
    const float* Wxo = (const float*)d_in[5];
    const float* Wxc = (const float*)d_in[6];
    const float* Whi = (const float*)d_in[7];
    const float* Whf = (const float*)d_in[8];
    const float* Who = (const float*)d_in[9];
    const float* Whc = (const float*)d_in[10];
    const float* bi  = (const float*)d_in[11];
    const float* bf_ = (const float*)d_in[12];
    const float* bo  = (const float*)d_in[13];
    const float* bc  = (const float*)d_in[14];

    char* ws = (char*)d_ws;
    unsigned short* Xq  = (unsigned short*)(ws + WS_XQ);
    unsigned short* WhB = (unsigned short*)(ws + WS_WHB);
    unsigned short* Hq  = (unsigned short*)(ws + WS_HQ);
    int* flags          = (int*)(ws + WS_FLAGS);

    hipMemsetAsync(flags, 0, FLAGS_BYTES, stream);

    hipLaunchKernelGGL(cvt_x, dim3(TT * BB * DD / 8 / 256), dim3(256), 0, stream, X, Xq);
    hipLaunchKernelGGL(pack_w, dim3(NWG * KTOT * 2 * 64 / 256), dim3(256), 0, stream,
                       Wxi, Wxf, Wxo, Wxc, Whi, Whf, Who, Whc, WhB);

    hipFuncSetAttribute((const void*)lstm_seq,
                        hipFuncAttributeMaxDynamicSharedMemorySize, LDS_BYTES);
    hipLaunchKernelGGL(lstm_seq, dim3(NWG), dim3(256), LDS_BYTES, stream,
                       Xq, WhB, Hq, flags, H0, C0, bi, bf_, bo, bc, (float*)d_out);
}

// Round 2
// 7464.203 us; speedup vs baseline: 1.1116x; 1.1116x over previous
//
#include <hip/hip_runtime.h>
#include <cstdint>

// ---------------- problem constants ----------------
#define TT 512
#define BB 64
#define DD 1024
#define HH 1024
#define NWG 128          // persistent workgroups; each owns 8 hidden units (32 gate cols)

typedef __attribute__((ext_vector_type(8))) __bf16 bf16x8;
typedef __attribute__((ext_vector_type(4))) float f32x4;

// ---- workspace layout (bytes) ----
// Xq   bf16[TT*BB*DD]            @ 0            (67,108,864)
// WhB  bf16[NWG*4*16*2*64*8]     @ 67,108,864   (16,777,216)
// Hq   bf16[(TT+1)*BB*HH]        @ 83,886,080   (67,239,936)
// flags int[(TT+1)*NWG]          @ 151,126,016  (   262,656)
#define WS_XQ    0
#define WS_WHB   67108864ULL
#define WS_HQ    83886080ULL
#define WS_FLAGS 151126016ULL
#define FLAGS_BYTES ((TT + 1) * NWG * 4)

__device__ __forceinline__ unsigned short f2bf(float f) {
    unsigned int u = __float_as_uint(f);
    u = (u + 0x7fffu + ((u >> 16) & 1u)) >> 16;
    return (unsigned short)u;
}

__device__ __forceinline__ float sigm(float x) {
    return 1.0f / (1.0f + __expf(-x));
}
__device__ __forceinline__ float tanh_f(float x) {
    float a = fabsf(x);
    float e = __expf(-2.0f * a);
    float t = (1.0f - e) / (1.0f + e);
    return copysignf(t, x);
}

__device__ __forceinline__ unsigned long long pack4bf(float a, float b, float c, float d) {
    return (unsigned long long)f2bf(a)
         | ((unsigned long long)f2bf(b) << 16)
         | ((unsigned long long)f2bf(c) << 32)
         | ((unsigned long long)f2bf(d) << 48);
}

// ---------------- kernel 1: convert X fp32 -> bf16 ----------------
__global__ void cvt_x(const float* __restrict__ X, unsigned short* __restrict__ Xq) {
    int i = blockIdx.x * blockDim.x + threadIdx.x;   // one thread per 8 elems
    const int n8 = TT * BB * DD / 8;
    if (i >= n8) return;
    const float4* s = (const float4*)X;
    float4 a = s[2 * i], b = s[2 * i + 1];
    union { unsigned short u[8]; uint4 q; } r;
    r.u[0] = f2bf(a.x); r.u[1] = f2bf(a.y); r.u[2] = f2bf(a.z); r.u[3] = f2bf(a.w);
    r.u[4] = f2bf(b.x); r.u[5] = f2bf(b.y); r.u[6] = f2bf(b.z); r.u[7] = f2bf(b.w);
    ((uint4*)Xq)[i] = r.q;
}

// ---------------- kernel 2: pack [Wx;Wh] into per-wave B-register order ----------------
// Linear element order: ((((wg*4 + kq)*16 + s)*2 + ct)*64 + lane)*8 + m
// lane holds B[k_global = kq*512 + s*32 + (lane>>4)*8 + m][col = ct*16 + (lane&15)]
// col j (0..31): gate = j>>3 (i,f,o,c), h = wg*8 + (j&7). k<1024 -> Wx row k, else Wh row k-1024.
__global__ void pack_w(const float* __restrict__ Wxi, const float* __restrict__ Wxf,
                       const float* __restrict__ Wxo, const float* __restrict__ Wxc,
                       const float* __restrict__ Whi, const float* __restrict__ Whf,
                       const float* __restrict__ Who, const float* __restrict__ Whc,
                       unsigned short* __restrict__ WhB) {
    int tid = blockIdx.x * blockDim.x + threadIdx.x;      // 0 .. 1,048,575 (one per 8 elems)
    int lane = tid & 63;
    int ct   = (tid >> 6) & 1;
    int s    = (tid >> 7) & 15;
    int kq   = (tid >> 11) & 3;
    int wg   = tid >> 13;
    int col  = ct * 16 + (lane & 15);
    int gate = col >> 3;
    int h    = wg * 8 + (col & 7);
    int kb   = kq * 512 + s * 32 + ((lane >> 4) & 3) * 8;   // k of element m=0

    const float* Wx[4] = {Wxi, Wxf, Wxo, Wxc};
    const float* Wh[4] = {Whi, Whf, Who, Whc};
    const float* W = (kb < 1024) ? (Wx[gate] + (size_t)kb * HH + h)
                                 : (Wh[gate] + (size_t)(kb - 1024) * HH + h);
    union { unsigned short u[8]; uint4 q; } r;
#pragma unroll
    for (int m = 0; m < 8; ++m) r.u[m] = f2bf(W[(size_t)m * HH]);
    *(uint4*)(WhB + (size_t)tid * 8) = r.q;
}

// ---------------- kernel 3: persistent LSTM recurrence ----------------
// 128 WGs x 512 threads (8 waves). Wave wv: rhalf = wv&1 (batch rows rhalf*32..+32),
// kq = wv>>1 (K quarter of 512). kq 0,1 = X part (no dependency); kq 2,3 = H part
// (polls flags, then reads Hq[t]). Each wave holds its 32 B-fragments in 128 VGPRs.
// Partial accumulators reduced through LDS; activation by thread (row,h).
__global__ void __launch_bounds__(512, 2)
lstm_seq(const unsigned short* __restrict__ Xq, const unsigned short* __restrict__ WhB,
         unsigned short* __restrict__ Hq, int* flags,
         const float* __restrict__ H0, const float* __restrict__ C0,
         const float* __restrict__ bi, const float* __restrict__ bfp,
         const float* __restrict__ bo, const float* __restrict__ bc,
         float* __restrict__ out) {
    __shared__ float gpart[4][64][34];   // [kq][row][col(+pad)]  34,816 B
    __shared__ float htile[64][8];       //                        2,048 B

    const int wg    = blockIdx.x;
    const int tid   = threadIdx.x;
    const int wv    = tid >> 6;
    const int lane  = tid & 63;
    const int quad  = lane >> 4;
    const int l15   = lane & 15;
    const int rhalf = wv & 1;
    const int kq    = wv >> 1;
    const int arow0 = rhalf * 32 + l15;      // GEMM A row for rt=0 (rt=1 adds 16)

    // activation identity: one (row, h) per thread
    const int arow = tid >> 3;               // 0..63
    const int hh   = tid & 7;
    const int hcol = wg * 8 + hh;
    const float Bi = bi[hcol], Bf = bfp[hcol], Bo = bo[hcol], Bc = bc[hcol];
    float Cr = C0[(size_t)arow * HH + hcol];

    // ---- preload this wave's 32 B-fragments into 128 VGPRs ----
    bf16x8 Breg[16][2];
    {
        const unsigned short* wp = WhB + (size_t)(wg * 4 + kq) * (16 * 2 * 64 * 8);
#pragma unroll
        for (int s = 0; s < 16; ++s)
#pragma unroll
            for (int ct = 0; ct < 2; ++ct)
                Breg[s][ct] = *(const bf16x8*)(wp + ((s * 2 + ct) * 64 + lane) * 8);
    }

    // ---- publish Hq[0] slice (agent scope -> LLC), then flag ----
    if (tid < 64) {
        const float* s = H0 + (size_t)tid * HH + wg * 8;
        unsigned long long a = pack4bf(s[0], s[1], s[2], s[3]);
        unsigned long long b = pack4bf(s[4], s[5], s[6], s[7]);
        unsigned long long* d = (unsigned long long*)(Hq + (size_t)tid * HH + wg * 8);
        __hip_atomic_store(d,     a, __ATOMIC_RELAXED, __HIP_MEMORY_SCOPE_AGENT);
        __hip_atomic_store(d + 1, b, __ATOMIC_RELAXED, __HIP_MEMORY_SCOPE_AGENT);
    }
    __syncthreads();
    if (tid == 0)
        __hip_atomic_store(&flags[wg], 1, __ATOMIC_RELEASE, __HIP_MEMORY_SCOPE_AGENT);

    for (int t = 0; t < TT; ++t) {
        f32x4 a00 = {0.f,0.f,0.f,0.f}, a01 = {0.f,0.f,0.f,0.f};
        f32x4 a10 = {0.f,0.f,0.f,0.f}, a11 = {0.f,0.f,0.f,0.f};

        if (kq < 2) {
            // ---- X part: no cross-WG dependency, starts immediately ----
            const unsigned short* xb = Xq + ((size_t)(t * BB + arow0)) * DD + kq * 512 + quad * 8;
#pragma unroll
            for (int s = 0; s < 16; ++s) {
                bf16x8 af0 = *(const bf16x8*)(xb + s * 32);
                bf16x8 af1 = *(const bf16x8*)(xb + 16 * DD + s * 32);
                a00 = __builtin_amdgcn_mfma_f32_16x16x32_bf16(af0, Breg[s][0], a00, 0, 0, 0);
                a01 = __builtin_amdgcn_mfma_f32_16x16x32_bf16(af0, Breg[s][1], a01, 0, 0, 0);
                a10 = __builtin_amdgcn_mfma_f32_16x16x32_bf16(af1, Breg[s][0], a10, 0, 0, 0);
                a11 = __builtin_amdgcn_mfma_f32_16x16x32_bf16(af1, Breg[s][1], a11, 0, 0, 0);
            }
        } else {
            // ---- wait for the 64 producer WGs covering this wave's K-range ----
            const int* fp = flags + (size_t)t * NWG + (kq - 2) * 64 + lane;
            while (__hip_atomic_load(fp, __ATOMIC_RELAXED, __HIP_MEMORY_SCOPE_AGENT) == 0)
                __builtin_amdgcn_s_sleep(1);
            // ---- H part ----
            const unsigned short* hb = Hq + ((size_t)(t * BB + arow0)) * HH + (kq - 2) * 512 + quad * 8;
#pragma unroll
            for (int s = 0; s < 16; ++s) {
                bf16x8 af0 = *(const bf16x8*)(hb + s * 32);
                bf16x8 af1 = *(const bf16x8*)(hb + 16 * HH + s * 32);
                a00 = __builtin_amdgcn_mfma_f32_16x16x32_bf16(af0, Breg[s][0], a00, 0, 0, 0);
                a01 = __builtin_amdgcn_mfma_f32_16x16x32_bf16(af0, Breg[s][1], a01, 0, 0, 0);
                a10 = __builtin_amdgcn_mfma_f32_16x16x32_bf16(af1, Breg[s][0], a10, 0, 0, 0);
                a11 = __builtin_amdgcn_mfma_f32_16x16x32_bf16(af1, Breg[s][1], a11, 0, 0, 0);
            }
        }

        // ---- C-frag (col=l15, row=quad*4+r) -> LDS partials ----
#pragma unroll
        for (int r = 0; r < 4; ++r) {
            int row0 = rhalf * 32 + quad * 4 + r;
            gpart[kq][row0][l15]           = a00[r];
            gpart[kq][row0][16 + l15]      = a01[r];
            gpart[kq][row0 + 16][l15]      = a10[r];
            gpart[kq][row0 + 16][16 + l15] = a11[r];
        }
        __syncthreads();

        // ---- activation: thread (arow, hh) sums 4 K-partials per gate ----
        {
            float gi = gpart[0][arow][hh]      + gpart[1][arow][hh]
                     + gpart[2][arow][hh]      + gpart[3][arow][hh]      + Bi;
            float gf = gpart[0][arow][8 + hh]  + gpart[1][arow][8 + hh]
                     + gpart[2][arow][8 + hh]  + gpart[3][arow][8 + hh]  + Bf;
            float go = gpart[0][arow][16 + hh] + gpart[1][arow][16 + hh]
                     + gpart[2][arow][16 + hh] + gpart[3][arow][16 + hh] + Bo;
            float gc = gpart[0][arow][24 + hh] + gpart[1][arow][24 + hh]
                     + gpart[2][arow][24 + hh] + gpart[3][arow][24 + hh] + Bc;
            float I = sigm(gi), F = sigm(gf), O = sigm(go), G = tanh_f(gc);
            Cr = F * Cr + I * G;
            htile[arow][hh] = O * tanh_f(Cr);
        }
        __syncthreads();

        // ---- coalesced stores: fp32 rows to out, bf16 rows to Hq[t+1] (agent scope) ----
        if (tid < 128) {
            int r2 = tid >> 1, half = tid & 1;
            float4 v = *(const float4*)&htile[r2][half * 4];
            *(float4*)(out + ((size_t)t * BB + r2) * HH + wg * 8 + half * 4) = v;
            unsigned long long pk = pack4bf(v.x, v.y, v.z, v.w);
            __hip_atomic_store(
                (unsigned long long*)(Hq + ((size_t)(t + 1) * BB + r2) * HH + wg * 8 + half * 4),
                pk, __ATOMIC_RELAXED, __HIP_MEMORY_SCOPE_AGENT);
            if (t == TT - 1) {   // H_f copy
                *(float4*)(out + (size_t)TT * BB * HH + (size_t)r2 * HH + wg * 8 + half * 4) = v;
            }
        }
        __syncthreads();   // all waves' stores drained (barrier implies vmcnt(0))
        if (tid == 0)
            __hip_atomic_store(flags + (size_t)(t + 1) * NWG + wg, 1,
                               __ATOMIC_RELEASE, __HIP_MEMORY_SCOPE_AGENT);
    }

    // ---- C_f ----
    float* cf = out + (size_t)TT * BB * HH + (size_t)BB * HH;
    cf[(size_t)arow * HH + hcol] = Cr;
}

// ---------------- launch ----------------
extern "C" void kernel_launch(void* const* d_in, const int* in_sizes, int n_in,
                              void* d_out, int out_size, void* d_ws, size_t ws_size,
                              hipStream_t stream) {
    const float* X   = (const float*)d_in[0];
    const float* H0  = (const float*)d_in[1];
    const float* C0  = (const float*)d_in[2];
    const float* Wxi = (const float*)d_in[3];
    const float* Wxf = (const float*)d_in[4];
    const float* Wxo = (const float*)d_in[5];
    const float* Wxc = (const float*)d_in[6];
    const float* Whi = (const float*)d_in[7];
    const float* Whf = (const float*)d_in[8];
    const float* Who = (const float*)d_in[9];
    const float* Whc = (const float*)d_in[10];
    const float* bi  = (const float*)d_in[11];
    const float* bf_ = (const float*)d_in[12];
    const float* bo  = (const float*)d_in[13];
    const float* bc  = (const float*)d_in[14];

    char* ws = (char*)d_ws;
    unsigned short* Xq  = (unsigned short*)(ws + WS_XQ);
    unsigned short* WhB = (unsigned short*)(ws + WS_WHB);
    unsigned short* Hq  = (unsigned short*)(ws + WS_HQ);
    int* flags          = (int*)(ws + WS_FLAGS);

    hipMemsetAsync(flags, 0, FLAGS_BYTES, stream);

    hipLaunchKernelGGL(cvt_x, dim3(TT * BB * DD / 8 / 256), dim3(256), 0, stream, X, Xq);
    hipLaunchKernelGGL(pack_w, dim3(4096), dim3(256), 0, stream,
                       Wxi, Wxf, Wxo, Wxc, Whi, Whf, Who, Whc, WhB);
    hipLaunchKernelGGL(lstm_seq, dim3(NWG), dim3(512), 0, stream,
                       Xq, WhB, Hq, flags, H0, C0, bi, bf_, bo, bc, (float*)d_out);
}

// Round 3
// 5571.151 us; speedup vs baseline: 1.4894x; 1.3398x over previous
//
#include <hip/hip_runtime.h>
#include <cstdint>

// ---------------- problem constants ----------------
#define TT 512
#define BB 64
#define DD 1024
#define HH 1024
#define NWG 128          // persistent workgroups; each owns 8 hidden units (32 gate cols)

typedef __attribute__((ext_vector_type(8))) __bf16 bf16x8;
typedef __attribute__((ext_vector_type(4))) float f32x4;

// ---- workspace layout (bytes) ----
#define WS_XQ    0
#define WS_WHB   67108864ULL
#define WS_HQ    83886080ULL
#define WS_FLAGS 151126016ULL
#define FLAGS_BYTES ((TT + 1) * NWG * 4)

__device__ __forceinline__ unsigned short f2bf(float f) {
    unsigned int u = __float_as_uint(f);
    u = (u + 0x7fffu + ((u >> 16) & 1u)) >> 16;
    return (unsigned short)u;
}

__device__ __forceinline__ float sigm(float x) {
    return 1.0f / (1.0f + __expf(-x));
}
__device__ __forceinline__ float tanh_f(float x) {
    float a = fabsf(x);
    float e = __expf(-2.0f * a);
    float t = (1.0f - e) / (1.0f + e);
    return copysignf(t, x);
}

__device__ __forceinline__ unsigned long long pack4bf(float a, float b, float c, float d) {
    return (unsigned long long)f2bf(a)
         | ((unsigned long long)f2bf(b) << 16)
         | ((unsigned long long)f2bf(c) << 32)
         | ((unsigned long long)f2bf(d) << 48);
}

// ---------------- kernel 1: convert X fp32 -> bf16 ----------------
__global__ void cvt_x(const float* __restrict__ X, unsigned short* __restrict__ Xq) {
    int i = blockIdx.x * blockDim.x + threadIdx.x;   // one thread per 8 elems
    const int n8 = TT * BB * DD / 8;
    if (i >= n8) return;
    const float4* s = (const float4*)X;
    float4 a = s[2 * i], b = s[2 * i + 1];
    union { unsigned short u[8]; uint4 q; } r;
    r.u[0] = f2bf(a.x); r.u[1] = f2bf(a.y); r.u[2] = f2bf(a.z); r.u[3] = f2bf(a.w);
    r.u[4] = f2bf(b.x); r.u[5] = f2bf(b.y); r.u[6] = f2bf(b.z); r.u[7] = f2bf(b.w);
    ((uint4*)Xq)[i] = r.q;
}

// ---------------- kernel 2: pack [Wx;Wh] into per-wave B-register order ----------------
// Linear element order: ((((wg*4 + kq)*16 + s)*2 + ct)*64 + lane)*8 + m
// lane holds B[k_global = kq*512 + s*32 + (lane>>4)*8 + m][col = ct*16 + (lane&15)]
// col j (0..31): gate = j>>3 (i,f,o,c), h = wg*8 + (j&7). k<1024 -> Wx row k, else Wh row k-1024.
__global__ void pack_w(const float* __restrict__ Wxi, const float* __restrict__ Wxf,
                       const float* __restrict__ Wxo, const float* __restrict__ Wxc,
                       const float* __restrict__ Whi, const float* __restrict__ Whf,
                       const float* __restrict__ Who, const float* __restrict__ Whc,
                       unsigned short* __restrict__ WhB) {
    int tid = blockIdx.x * blockDim.x + threadIdx.x;      // 0 .. 1,048,575 (one per 8 elems)
    int lane = tid & 63;
    int ct   = (tid >> 6) & 1;
    int s    = (tid >> 7) & 15;
    int kq   = (tid >> 11) & 3;
    int wg   = tid >> 13;
    int col  = ct * 16 + (lane & 15);
    int gate = col >> 3;
    int h    = wg * 8 + (col & 7);
    int kb   = kq * 512 + s * 32 + ((lane >> 4) & 3) * 8;   // k of element m=0

    const float* Wx[4] = {Wxi, Wxf, Wxo, Wxc};
    const float* Wh[4] = {Whi, Whf, Who, Whc};
    const float* W = (kb < 1024) ? (Wx[gate] + (size_t)kb * HH + h)
                                 : (Wh[gate] + (size_t)(kb - 1024) * HH + h);
    union { unsigned short u[8]; uint4 q; } r;
#pragma unroll
    for (int m = 0; m < 8; ++m) r.u[m] = f2bf(W[(size_t)m * HH]);
    *(uint4*)(WhB + (size_t)tid * 8) = r.q;
}

// ---------------- kernel 3: persistent LSTM recurrence ----------------
// 128 WGs x 512 threads (8 waves). Wave wv: rhalf = wv&1 (batch rows rhalf*32..+32),
// kq = wv>>1 (K quarter of 512). kq 0,1 = X part (no dependency); kq 2,3 = H part
// (polls flags, then reads Hq[t]). Weights live in 128 VGPRs per wave.
//
// SYNC DESIGN (no RELEASE anywhere — agent-release on gfx95x lowers to
// buffer_wbl2 sc1 = full per-XCD L2 writeback, ~10k+ cycles, once per WG per
// step = the round-1/2 14us/step floor):
//   * Hq data stores:  relaxed AGENT-scope atomic stores (sc1 -> LLC, the
//     coherence point). Fresh address each step, so consumer L2s can't hold
//     stale copies (their fetch happens only after the flag is seen, and all
//     8 slice-owners of a 128B line are polled before any fetch).
//   * __syncthreads() implies per-wave s_waitcnt vmcnt(0) -> all Hq stores
//     acked at LLC before any thread passes the barrier.
//   * flag store: relaxed AGENT-scope atomic AFTER the barrier -> ordered
//     after data with zero cache maintenance.
__global__ void __launch_bounds__(512, 2)
lstm_seq(const unsigned short* __restrict__ Xq, const unsigned short* __restrict__ WhB,
         unsigned short* __restrict__ Hq, int* flags,
         const float* __restrict__ H0, const float* __restrict__ C0,
         const float* __restrict__ bi, const float* __restrict__ bfp,
         const float* __restrict__ bo, const float* __restrict__ bc,
         float* __restrict__ out) {
    __shared__ float gpart[4][64][36];   // pad 36: act-reads (4q+h)%32 -> 2-way = free
    __shared__ float htile[64][8];

    const int wg    = blockIdx.x;
    const int tid   = threadIdx.x;
    const int wv    = tid >> 6;
    const int lane  = tid & 63;
    const int quad  = lane >> 4;
    const int l15   = lane & 15;
    const int rhalf = wv & 1;
    const int kq    = wv >> 1;
    const int arow0 = rhalf * 32 + l15;      // GEMM A row for rt=0 (rt=1 adds 16)

    // activation identity: one (row, h) per thread
    const int arow = tid >> 3;               // 0..63
    const int hh   = tid & 7;
    const int hcol = wg * 8 + hh;
    const float Bi = bi[hcol], Bf = bfp[hcol], Bo = bo[hcol], Bc = bc[hcol];
    float Cr = C0[(size_t)arow * HH + hcol];

    // ---- preload this wave's 32 B-fragments into 128 VGPRs ----
    bf16x8 Breg[16][2];
    {
        const unsigned short* wp = WhB + (size_t)(wg * 4 + kq) * (16 * 2 * 64 * 8);
#pragma unroll
        for (int s = 0; s < 16; ++s)
#pragma unroll
            for (int ct = 0; ct < 2; ++ct)
                Breg[s][ct] = *(const bf16x8*)(wp + ((s * 2 + ct) * 64 + lane) * 8);
    }

    // ---- publish Hq[0] slice (relaxed agent -> LLC), barrier, then relaxed flag ----
    if (tid < 64) {
        const float* s = H0 + (size_t)tid * HH + wg * 8;
        unsigned long long a = pack4bf(s[0], s[1], s[2], s[3]);
        unsigned long long b = pack4bf(s[4], s[5], s[6], s[7]);
        unsigned long long* d = (unsigned long long*)(Hq + (size_t)tid * HH + wg * 8);
        __hip_atomic_store(d,     a, __ATOMIC_RELAXED, __HIP_MEMORY_SCOPE_AGENT);
        __hip_atomic_store(d + 1, b, __ATOMIC_RELAXED, __HIP_MEMORY_SCOPE_AGENT);
    }
    __syncthreads();   // drains vmcnt -> Hq[0] visible at LLC
    if (tid == 0)
        __hip_atomic_store(&flags[wg], 1, __ATOMIC_RELAXED, __HIP_MEMORY_SCOPE_AGENT);

    for (int t = 0; t < TT; ++t) {
        f32x4 a00 = {0.f,0.f,0.f,0.f}, a01 = {0.f,0.f,0.f,0.f};
        f32x4 a10 = {0.f,0.f,0.f,0.f}, a11 = {0.f,0.f,0.f,0.f};

        if (kq < 2) {
            // ---- X part: no cross-WG dependency, starts immediately ----
            const unsigned short* xb = Xq + ((size_t)(t * BB + arow0)) * DD + kq * 512 + quad * 8;
#pragma unroll
            for (int s = 0; s < 16; ++s) {
                bf16x8 af0 = *(const bf16x8*)(xb + s * 32);
                bf16x8 af1 = *(const bf16x8*)(xb + 16 * DD + s * 32);
                a00 = __builtin_amdgcn_mfma_f32_16x16x32_bf16(af0, Breg[s][0], a00, 0, 0, 0);
                a01 = __builtin_amdgcn_mfma_f32_16x16x32_bf16(af0, Breg[s][1], a01, 0, 0, 0);
                a10 = __builtin_amdgcn_mfma_f32_16x16x32_bf16(af1, Breg[s][0], a10, 0, 0, 0);
                a11 = __builtin_amdgcn_mfma_f32_16x16x32_bf16(af1, Breg[s][1], a11, 0, 0, 0);
            }
        } else {
            // ---- wait for the 64 producer WGs covering this wave's K-range ----
            const int* fp = flags + (size_t)t * NWG + (kq - 2) * 64 + lane;
            while (__hip_atomic_load(fp, __ATOMIC_RELAXED, __HIP_MEMORY_SCOPE_AGENT) == 0)
                __builtin_amdgcn_s_sleep(1);
            // ---- H part ----
            const unsigned short* hb = Hq + ((size_t)(t * BB + arow0)) * HH + (kq - 2) * 512 + quad * 8;
#pragma unroll
            for (int s = 0; s < 16; ++s) {
                bf16x8 af0 = *(const bf16x8*)(hb + s * 32);
                bf16x8 af1 = *(const bf16x8*)(hb + 16 * HH + s * 32);
                a00 = __builtin_amdgcn_mfma_f32_16x16x32_bf16(af0, Breg[s][0], a00, 0, 0, 0);
                a01 = __builtin_amdgcn_mfma_f32_16x16x32_bf16(af0, Breg[s][1], a01, 0, 0, 0);
                a10 = __builtin_amdgcn_mfma_f32_16x16x32_bf16(af1, Breg[s][0], a10, 0, 0, 0);
                a11 = __builtin_amdgcn_mfma_f32_16x16x32_bf16(af1, Breg[s][1], a11, 0, 0, 0);
            }
        }

        // ---- C-frag (col=l15, row=quad*4+r) -> LDS partials ----
#pragma unroll
        for (int r = 0; r < 4; ++r) {
            int row0 = rhalf * 32 + quad * 4 + r;
            gpart[kq][row0][l15]           = a00[r];
            gpart[kq][row0][16 + l15]      = a01[r];
            gpart[kq][row0 + 16][l15]      = a10[r];
            gpart[kq][row0 + 16][16 + l15] = a11[r];
        }
        __syncthreads();

        // ---- activation: thread (arow, hh) sums 4 K-partials per gate ----
        {
            float gi = gpart[0][arow][hh]      + gpart[1][arow][hh]
                     + gpart[2][arow][hh]      + gpart[3][arow][hh]      + Bi;
            float gf = gpart[0][arow][8 + hh]  + gpart[1][arow][8 + hh]
                     + gpart[2][arow][8 + hh]  + gpart[3][arow][8 + hh]  + Bf;
            float go = gpart[0][arow][16 + hh] + gpart[1][arow][16 + hh]
                     + gpart[2][arow][16 + hh] + gpart[3][arow][16 + hh] + Bo;
            float gc = gpart[0][arow][24 + hh] + gpart[1][arow][24 + hh]
                     + gpart[2][arow][24 + hh] + gpart[3][arow][24 + hh] + Bc;
            float I = sigm(gi), F = sigm(gf), O = sigm(go), G = tanh_f(gc);
            Cr = F * Cr + I * G;
            htile[arow][hh] = O * tanh_f(Cr);
        }
        __syncthreads();

        // ---- coalesced stores: fp32 rows to out, bf16 rows to Hq[t+1] (relaxed agent) ----
        if (tid < 128) {
            int r2 = tid >> 1, half = tid & 1;
            float4 v = *(const float4*)&htile[r2][half * 4];
            *(float4*)(out + ((size_t)t * BB + r2) * HH + wg * 8 + half * 4) = v;
            unsigned long long pk = pack4bf(v.x, v.y, v.z, v.w);
            __hip_atomic_store(
                (unsigned long long*)(Hq + ((size_t)(t + 1) * BB + r2) * HH + wg * 8 + half * 4),
                pk, __ATOMIC_RELAXED, __HIP_MEMORY_SCOPE_AGENT);
            if (t == TT - 1) {   // H_f copy
                *(float4*)(out + (size_t)TT * BB * HH + (size_t)r2 * HH + wg * 8 + half * 4) = v;
            }
        }
        __syncthreads();   // per-wave vmcnt(0) -> Hq[t+1] stores acked at LLC
        if (tid == 0)
            __hip_atomic_store(flags + (size_t)(t + 1) * NWG + wg, 1,
                               __ATOMIC_RELAXED, __HIP_MEMORY_SCOPE_AGENT);
    }

    // ---- C_f ----
    float* cf = out + (size_t)TT * BB * HH + (size_t)BB * HH;
    cf[(size_t)arow * HH + hcol] = Cr;
}

// ---------------- launch ----------------
extern "C" void kernel_launch(void* const* d_in, const int* in_sizes, int n_in,
                              void* d_out, int out_size, void* d_ws, size_t ws_size,
                              hipStream_t stream) {
    const float* X   = (const float*)d_in[0];
    const float* H0  = (const float*)d_in[1];
    const float* C0  = (const float*)d_in[2];
    const float* Wxi = (const float*)d_in[3];
    const float* Wxf = (const float*)d_in[4];
    const float* Wxo = (const float*)d_in[5];
    const float* Wxc = (const float*)d_in[6];
    const float* Whi = (const float*)d_in[7];
    const float* Whf = (const float*)d_in[8];
    const float* Who = (const float*)d_in[9];
    const float* Whc = (const float*)d_in[10];
    const float* bi  = (const float*)d_in[11];
    const float* bf_ = (const float*)d_in[12];
    const float* bo  = (const float*)d_in[13];
    const float* bc  = (const float*)d_in[14];

    char* ws = (char*)d_ws;
    unsigned short* Xq  = (unsigned short*)(ws + WS_XQ);
    unsigned short* WhB = (unsigned short*)(ws + WS_WHB);
    unsigned short* Hq  = (unsigned short*)(ws + WS_HQ);
    int* flags          = (int*)(ws + WS_FLAGS);

    hipMemsetAsync(flags, 0, FLAGS_BYTES, stream);

    hipLaunchKernelGGL(cvt_x, dim3(TT * BB * DD / 8 / 256), dim3(256), 0, stream, X, Xq);
    hipLaunchKernelGGL(pack_w, dim3(4096), dim3(256), 0, stream,
                       Wxi, Wxf, Wxo, Wxc, Whi, Whf, Who, Whc, WhB);
    hipLaunchKernelGGL(lstm_seq, dim3(NWG), dim3(512), 0, stream,
                       Xq, WhB, Hq, flags, H0, C0, bi, bf_, bo, bc, (float*)d_out);
}